// Round 4
// baseline (4282.434 us; speedup 1.0000x reference)
//
#include <hip/hip_runtime.h>
#include <hip/hip_bf16.h>
#include <math.h>

#define BATCH 2
#define NPTS  8192
#define CIN   32
#define HID   128
#define COUT  64
#define EIN   67
#define KNN   16

__device__ __forceinline__ float u2f(unsigned short u) {
    return __uint_as_float(((unsigned int)u) << 16);
}
__device__ __forceinline__ unsigned short f2u16(float f) {   // RNE fp32->bf16
    unsigned int u = __float_as_uint(f);
    unsigned int r = (u + 0x7FFFu + ((u >> 16) & 1u)) >> 16;
    return (unsigned short)r;
}

__device__ __forceinline__ float gelu_tanh(float u) {
    float u3 = u * u * u;
    float t = tanhf(0.7978845608028654f * (u + 0.044715f * u3));
    return 0.5f * u * (1.0f + t);
}

// LayerNorm stats over 128 values held one-per-thread (2 waves).
__device__ __forceinline__ void ln_stats(float h, float* red, int tid,
                                         float& mu, float& rstd) {
    int lane = tid & 63, wv = tid >> 6;
    float s1 = h, s2 = h * h;
#pragma unroll
    for (int off = 1; off < 64; off <<= 1) {
        s1 += __shfl_xor(s1, off, 64);
        s2 += __shfl_xor(s2, off, 64);
    }
    __syncthreads();                 // protect red from any previous use
    if (lane == 0) { red[wv * 2] = s1; red[wv * 2 + 1] = s2; }
    __syncthreads();
    float S1 = red[0] + red[2];
    float S2 = red[1] + red[3];
    mu = S1 * (1.0f / HID);
    float var = S2 * (1.0f / HID) - mu * mu;
    rstd = 1.0f / sqrtf(var + 1e-5f);
}

// One block (128 threads) per output point. Zero global scratch.
__global__ __launch_bounds__(128) void fused_kernel(
    const float* __restrict__ verts, const float* __restrict__ feats,
    const float* __restrict__ W1, const float* __restrict__ b1,
    const float* __restrict__ g1, const float* __restrict__ be1,
    const float* __restrict__ W2, const float* __restrict__ b2,
    const float* __restrict__ Wo1, const float* __restrict__ bo1,
    const float* __restrict__ go, const float* __restrict__ beo,
    const float* __restrict__ Wo2, const float* __restrict__ bo2,
    float* __restrict__ out)
{
    __shared__ float w1s[EIN * HID];            // fp32 [c][t]  (34304 B)
    __shared__ unsigned short w2u[HID * COUT];  // bf16 [t][o]  (16384 B)
    __shared__ float e[EIN + 1];
    __shared__ float gh[HID];
    __shared__ float red[4];
    __shared__ float part[HID];
    __shared__ float m[COUT];
    __shared__ float wd[2][KNN];
    __shared__ int   wi[2][KNN];
    __shared__ int   nbr[KNN];

    const int tid  = threadIdx.x;
    const int lane = tid & 63;
    const int wv   = tid >> 6;
    const int pt   = blockIdx.x;                // 0 .. BATCH*NPTS-1
    const int b    = pt >> 13;
    const int i    = pt & (NPTS - 1);

    // ---- stage weights into LDS ----
    for (int x = tid; x < EIN * HID; x += 128) w1s[x] = W1[x];
    for (int x = tid; x < HID * COUT; x += 128) w2u[x] = f2u16(W2[x]);

    const float* vb = verts + (size_t)b * NPTS * 3;
    const float xi = vb[3 * i + 0];
    const float yi = vb[3 * i + 1];
    const float zi = vb[3 * i + 2];
    const float sqi = xi * xi + yi * yi + zi * zi;

    // self features into e[32..63] (barrier below covers this)
    const float* selfF = feats + ((size_t)b * NPTS + i) * CIN;
    if (tid >= 32 && tid < 64) e[tid] = selfF[tid - 32];

    // ---- KNN: each wave scans half the candidates ----
    float bd[KNN]; int bi_[KNN];
#pragma unroll
    for (int t = 0; t < KNN; ++t) { bd[t] = INFINITY; bi_[t] = 0x7FFFFFFF; }

    for (int t = 0; t < NPTS / 128; ++t) {
        int j = (t << 7) + (wv << 6) + lane;
        float px = vb[3 * j + 0];
        float py = vb[3 * j + 1];
        float pz = vb[3 * j + 2];
        float sqj = px * px + py * py + pz * pz;
        float dot = xi * px + yi * py + zi * pz;
        float d = (sqi + sqj) - 2.0f * dot;

        bool better = (d < bd[KNN - 1]) || (d == bd[KNN - 1] && j < bi_[KNN - 1]);
        if (better) {
            bd[KNN - 1] = d; bi_[KNN - 1] = j;
#pragma unroll
            for (int s = KNN - 1; s >= 1; --s) {
                bool sw = (bd[s] < bd[s - 1]) ||
                          (bd[s] == bd[s - 1] && bi_[s] < bi_[s - 1]);
                if (sw) {
                    float td = bd[s]; bd[s] = bd[s - 1]; bd[s - 1] = td;
                    int   ti = bi_[s]; bi_[s] = bi_[s - 1]; bi_[s - 1] = ti;
                }
            }
        }
    }

    // wave-level merge: 16 argmin-pops over 64 sorted lane-lists
    for (int r = 0; r < KNN; ++r) {
        float cd = bd[0]; int ci = bi_[0];
        float md = cd;    int mi = ci;
#pragma unroll
        for (int off = 1; off < 64; off <<= 1) {
            float od = __shfl_xor(md, off, 64);
            int   oi = __shfl_xor(mi, off, 64);
            if (od < md || (od == md && oi < mi)) { md = od; mi = oi; }
        }
        if (lane == 0) { wd[wv][r] = md; wi[wv][r] = mi; }
        if (ci == mi) {   // candidate indices unique -> exactly one owner
#pragma unroll
            for (int s = 0; s < KNN - 1; ++s) { bd[s] = bd[s + 1]; bi_[s] = bi_[s + 1]; }
            bd[KNN - 1] = INFINITY; bi_[KNN - 1] = 0x7FFFFFFF;
        }
    }
    __syncthreads();

    // cross-wave merge of two sorted 16-lists (p0+p1 == r <= 15, so no OOB)
    if (tid == 0) {
        int p0 = 0, p1 = 0;
        for (int r = 0; r < KNN; ++r) {
            float d0 = wd[0][p0], d1 = wd[1][p1];
            int   i0 = wi[0][p0], i1 = wi[1][p1];
            bool take0 = (d0 < d1) || (d0 == d1 && i0 < i1);
            if (take0) { nbr[r] = i0; ++p0; } else { nbr[r] = i1; ++p1; }
        }
    }
    __syncthreads();

    // ---- edge MLP over K neighbors + mean ----
    const float b1t  = b1[tid];
    const float g1t  = g1[tid];
    const float be1t = be1[tid];

    const int o    = tid & 63;
    const int half = tid >> 6;
    float acc = 0.0f;

    for (int k = 0; k < KNN; ++k) {
        int j = nbr[k];
        if (tid < 32) e[tid] = feats[((size_t)b * NPTS + j) * CIN + tid];
        if (tid >= 64 && tid < 67) {
            float nv  = vb[3 * j + (tid - 64)];
            float svc = (tid == 64) ? xi : ((tid == 65) ? yi : zi);
            e[tid] = nv - svc;
        }
        __syncthreads();

        float h = 0.0f;
#pragma unroll
        for (int c = 0; c < EIN; ++c) h = fmaf(e[c], w1s[c * HID + tid], h);
        h += b1t;

        float mu, rstd;
        ln_stats(h, red, tid, mu, rstd);
        float xn = (h - mu) * rstd * g1t + be1t;
        gh[tid] = gelu_tanh(xn);
        __syncthreads();

        float p = 0.0f;
        const int tb = half * 64;
#pragma unroll
        for (int t = 0; t < 64; ++t) {
            int tt = tb + t;
            p = fmaf(gh[tt], u2f(w2u[tt * COUT + o]), p);
        }
        acc += p;
        __syncthreads();   // before e/gh are overwritten next iteration
    }

    part[tid] = acc;
    __syncthreads();
    if (tid < 64) {
        m[tid] = (part[tid] + part[64 + tid]) * (1.0f / KNN) + b2[tid];
    }
    __syncthreads();

    // ---- point MLP: 64 -> 128 -> LN -> GELU -> 64 ----
    float ho = 0.0f;
#pragma unroll
    for (int c = 0; c < COUT; ++c) ho = fmaf(m[c], Wo1[c * HID + tid], ho);
    ho += bo1[tid];

    float mu2, rstd2;
    ln_stats(ho, red, tid, mu2, rstd2);
    float xo = (ho - mu2) * rstd2 * go[tid] + beo[tid];
    gh[tid] = gelu_tanh(xo);
    __syncthreads();

    float p2 = 0.0f;
    const int tb = half * 64;
#pragma unroll
    for (int t = 0; t < 64; ++t) {
        int tt = tb + t;
        p2 = fmaf(gh[tt], Wo2[tt * COUT + o], p2);
    }
    part[tid] = p2;
    __syncthreads();
    if (tid < 64) {
        float res = part[tid] + part[64 + tid] + bo2[tid];
        out[(size_t)pt * COUT + tid] = res;
    }
}

extern "C" void kernel_launch(void* const* d_in, const int* in_sizes, int n_in,
                              void* d_out, int out_size, void* d_ws, size_t ws_size,
                              hipStream_t stream) {
    const float* verts = (const float*)d_in[0];
    const float* feats = (const float*)d_in[1];
    const float* W1  = (const float*)d_in[2];
    const float* b1  = (const float*)d_in[3];
    const float* g1  = (const float*)d_in[4];
    const float* be1 = (const float*)d_in[5];
    const float* W2  = (const float*)d_in[6];
    const float* b2  = (const float*)d_in[7];
    const float* Wo1 = (const float*)d_in[8];
    const float* bo1 = (const float*)d_in[9];
    const float* go  = (const float*)d_in[10];
    const float* beo = (const float*)d_in[11];
    const float* Wo2 = (const float*)d_in[12];
    const float* bo2 = (const float*)d_in[13];
    float* out = (float*)d_out;

    (void)in_sizes; (void)n_in; (void)d_ws; (void)ws_size; (void)out_size;

    fused_kernel<<<BATCH * NPTS, 128, 0, stream>>>(
        verts, feats, W1, b1, g1, be1, W2, b2,
        Wo1, bo1, go, beo, Wo2, bo2, out);
}

// Round 5
// 927.907 us; speedup vs baseline: 4.6152x; 4.6152x over previous
//
#include <hip/hip_runtime.h>
#include <hip/hip_bf16.h>
#include <math.h>

#define BATCH 2
#define NPTS  8192
#define CIN   32
#define HID   128
#define COUT  64
#define EIN   67
#define KNN   16

#define TILE  1024   // knn candidate tile (points per LDS stage)
#define CAP   128    // survivor cap per wave

typedef unsigned short u16;
typedef unsigned long long u64;

__device__ __forceinline__ float bl(unsigned u) { return __uint_as_float(u << 16); }
__device__ __forceinline__ float bh(unsigned u) { return __uint_as_float(u & 0xFFFF0000u); }
__device__ __forceinline__ u16 f2b(float f) {   // RNE fp32->bf16
    unsigned u = __float_as_uint(f);
    return (u16)((u + 0x7FFFu + ((u >> 16) & 1u)) >> 16);
}
// tanh-approximate GELU: x * e^{2a}/(e^{2a}+1), a = 0.79788456(x + 0.044715 x^3)
__device__ __forceinline__ float gelu_t(float x) {
    float u = 1.5957691216057308f * (x + 0.044715f * x * x * x);
    float ex = __expf(u);
    return x * ex / (ex + 1.0f);
}

// ======================= KNN: 2-pass threshold =======================
// 1 wave per point, 4 waves/block. Candidates staged in LDS tiles shared
// by the block. tau = 16th smallest of 64 lane-minima >= d_(16) (16
// distinct candidates <= tau), so survivors contain the true top-16.
__global__ __launch_bounds__(256) void knn_kernel(const float* __restrict__ verts,
                                                  int* nbr_out_rows) {
    __shared__ float4 tilebuf[TILE];
    __shared__ float  bufD[4][CAP];
    __shared__ int    bufJ[4][CAP];

    const int tid = threadIdx.x, lane = tid & 63, wv = tid >> 6;
    const int pt = blockIdx.x * 4 + wv;
    const int b = pt >> 13, i = pt & (NPTS - 1);
    const float* vb = verts + (size_t)b * NPTS * 3;

    const float xi = vb[3 * i], yi = vb[3 * i + 1], zi = vb[3 * i + 2];
    const float sqi = xi * xi + yi * yi + zi * zi;

    // ---- pass 1: per-lane min over 128 candidates ----
    float m_d = INFINITY; int m_j = 0;
    for (int t = 0; t < NPTS / TILE; ++t) {
        __syncthreads();
        for (int s = 0; s < TILE / 256; ++s) {
            int p = t * TILE + s * 256 + tid;
            float px = vb[3 * p], py = vb[3 * p + 1], pz = vb[3 * p + 2];
            tilebuf[s * 256 + tid] = make_float4(px, py, pz, px * px + py * py + pz * pz);
        }
        __syncthreads();
        for (int it = 0; it < TILE / 64; ++it) {
            int jl = it * 64 + lane;
            float4 c = tilebuf[jl];
            float d = (sqi + c.w) - 2.0f * (xi * c.x + yi * c.y + zi * c.z);
            if (d < m_d) { m_d = d; m_j = t * TILE + jl; }  // ascending scan + strict <
        }
    }

    // ---- tau = 16th argmin-pop over the 64 lane minima ----
    float pd = m_d; int pj = m_j;
    float tau = INFINITY;
    for (int r = 0; r < KNN; ++r) {
        float md = pd; int mj = pj;
#pragma unroll
        for (int off = 1; off < 64; off <<= 1) {
            float od = __shfl_xor(md, off, 64);
            int   oj = __shfl_xor(mj, off, 64);
            if (od < md || (od == md && oj < mj)) { md = od; mj = oj; }
        }
        tau = md;
        if (pj == mj && pd == md) { pd = INFINITY; pj = 0x7FFFFFFF; }
    }

    // ---- pass 2: ballot-compact all candidates with d <= tau ----
    int base = 0;
    for (int t = 0; t < NPTS / TILE; ++t) {
        __syncthreads();
        for (int s = 0; s < TILE / 256; ++s) {
            int p = t * TILE + s * 256 + tid;
            float px = vb[3 * p], py = vb[3 * p + 1], pz = vb[3 * p + 2];
            tilebuf[s * 256 + tid] = make_float4(px, py, pz, px * px + py * py + pz * pz);
        }
        __syncthreads();
        for (int it = 0; it < TILE / 64; ++it) {
            int jl = it * 64 + lane;
            float4 c = tilebuf[jl];
            float d = (sqi + c.w) - 2.0f * (xi * c.x + yi * c.y + zi * c.z);
            bool pred = (d <= tau);
            u64 mask = __ballot(pred);
            if (pred) {
                int pos = base + __popcll(mask & ((1ull << lane) - 1ull));
                if (pos < CAP) { bufD[wv][pos] = d; bufJ[wv][pos] = t * TILE + jl; }
            }
            base += (int)__popcll(mask);
        }
    }
    int ns = (base > CAP) ? CAP : base;   // ns >= 16 guaranteed

    // ---- exact (d, idx)-lexicographic top-16 among survivors ----
    float d0 = (lane < ns)      ? bufD[wv][lane]      : INFINITY;
    int   j0 = (lane < ns)      ? bufJ[wv][lane]      : 0x7FFFFFFF;
    float d1 = (64 + lane < ns) ? bufD[wv][64 + lane] : INFINITY;
    int   j1 = (64 + lane < ns) ? bufJ[wv][64 + lane] : 0x7FFFFFFF;
    int myout = 0;
    for (int r = 0; r < KNN; ++r) {
        bool use0 = (d0 < d1) || (d0 == d1 && j0 < j1);
        float cd = use0 ? d0 : d1; int cj = use0 ? j0 : j1;
        float md = cd; int mj = cj;
#pragma unroll
        for (int off = 1; off < 64; off <<= 1) {
            float od = __shfl_xor(md, off, 64);
            int   oj = __shfl_xor(mj, off, 64);
            if (od < md || (od == md && oj < mj)) { md = od; mj = oj; }
        }
        if (lane == r) myout = mj;
        if (cj == mj && cd == md) {
            if (use0) { d0 = INFINITY; j0 = 0x7FFFFFFF; }
            else      { d1 = INFINITY; j1 = 0x7FFFFFFF; }
        }
    }
    if (lane < KNN) nbr_out_rows[pt * 64 + lane] = myout;  // stash in out-row head
}

// ======================= fused MLP =======================
// 1 block (128 threads) per point. 16-edge register blocking; transposed
// bf16 weight tiles in LDS read as uint4 (8 halves / ds_read_b128).
__global__ __launch_bounds__(128) void mlp_kernel(
    const float* __restrict__ verts, const float* __restrict__ feats,
    const float* __restrict__ W1, const float* __restrict__ b1,
    const float* __restrict__ g1, const float* __restrict__ be1,
    const float* __restrict__ W2, const float* __restrict__ b2,
    const float* __restrict__ Wo1, const float* __restrict__ bo1,
    const float* __restrict__ go, const float* __restrict__ beo,
    const float* __restrict__ Wo2, const float* __restrict__ bo2,
    float* out)   // row heads hold the knn indices (as ints) on entry
{
    __shared__ u16   w1h[HID][72];    // [t][c], stride 36 words (bank-balanced)
    __shared__ u16   w2h[COUT][136];  // [o][t], stride 68 words (bank-balanced)
    __shared__ float em[KNN][68];     // edge features (fp32, broadcast-read)
    __shared__ float pm[KNN][132];    // gelu outputs; later reused as partm[2][16][64]
    __shared__ float redw[2][32];
    __shared__ float msh[COUT];
    __shared__ float part2[2][COUT];
    __shared__ int   nbr[KNN];

    const int tid = threadIdx.x, lane = tid & 63, wv = tid >> 6;
    const int pt = blockIdx.x, b = pt >> 13, i = pt & (NPTS - 1);

    if (tid < KNN) nbr[tid] = ((const int*)out)[pt * 64 + tid];
    __syncthreads();

    // ---- stage weights (transposed, bf16) ----
    for (int x = tid; x < EIN * HID; x += 128) { int c = x >> 7, t = x & 127; w1h[t][c] = f2b(W1[x]); }
    w1h[tid][67] = 0;   // zero pad col 67 (tail reads c=64..67)
    for (int x = tid; x < HID * COUT; x += 128) { int t = x >> 6, o = x & 63; w2h[o][t] = f2b(W2[x]); }

    // ---- stage edge features em[k][0..66], em[k][67]=0 ----
    const float* vb = verts + (size_t)b * NPTS * 3;
    const float* fb = feats + (size_t)b * NPTS * CIN;
    {
        int kg = tid >> 5, c = tid & 31;
        for (int kk = 0; kk < 4; ++kk) {
            int k = kk * 4 + kg;
            em[k][c] = fb[(size_t)nbr[k] * CIN + c];
        }
        if (tid < 32) {
            float sf = fb[(size_t)i * CIN + tid];
            for (int k = 0; k < KNN; ++k) em[k][32 + tid] = sf;
        }
        int idx = tid - 64;
        if (idx >= 0 && idx < 48) {
            int k = idx / 3, c3 = idx - 3 * k;
            em[k][64 + c3] = vb[3 * nbr[k] + c3] - vb[3 * i + c3];
        }
        if (tid >= 112) em[tid - 112][67] = 0.0f;
    }
    __syncthreads();

    // ---- GEMM1: h[k][tid] = sum_c em[k][c] * W1[c][tid] ----
    float h[KNN];
#pragma unroll
    for (int k = 0; k < KNN; ++k) h[k] = 0.0f;
#pragma unroll
    for (int c8 = 0; c8 < 64; c8 += 8) {
        uint4 wp = *(const uint4*)&w1h[tid][c8];
        float w0 = bl(wp.x), wA = bh(wp.x), w2v = bl(wp.y), w3 = bh(wp.y);
        float w4 = bl(wp.z), w5 = bh(wp.z), w6 = bl(wp.w), w7 = bh(wp.w);
#pragma unroll
        for (int k = 0; k < KNN; ++k) {
            float4 ea = *(const float4*)&em[k][c8];
            float4 eb = *(const float4*)&em[k][c8 + 4];
            h[k] = fmaf(ea.x, w0, fmaf(ea.y, wA, fmaf(ea.z, w2v, fmaf(ea.w, w3,
                   fmaf(eb.x, w4, fmaf(eb.y, w5, fmaf(eb.z, w6, fmaf(eb.w, w7, h[k]))))))));
        }
    }
    {   // tail c = 64..67 (em[.][67] = 0, w1h[.][67] = 0)
        uint2 wp = *(const uint2*)&w1h[tid][64];
        float w0 = bl(wp.x), wA = bh(wp.x), w2v = bl(wp.y), w3 = bh(wp.y);
#pragma unroll
        for (int k = 0; k < KNN; ++k) {
            float4 ea = *(const float4*)&em[k][64];
            h[k] = fmaf(ea.x, w0, fmaf(ea.y, wA, fmaf(ea.z, w2v, fmaf(ea.w, w3, h[k]))));
        }
    }

    // ---- LayerNorm (per edge, across 128 channels) + GELU ----
    const float b1t = b1[tid], g1t = g1[tid], be1t = be1[tid];
    float s1[KNN], s2[KNN];
#pragma unroll
    for (int k = 0; k < KNN; ++k) { h[k] += b1t; s1[k] = h[k]; s2[k] = h[k] * h[k]; }
#pragma unroll
    for (int off = 1; off < 64; off <<= 1) {
#pragma unroll
        for (int k = 0; k < KNN; ++k) {
            s1[k] += __shfl_xor(s1[k], off, 64);
            s2[k] += __shfl_xor(s2[k], off, 64);
        }
    }
    if (lane == 0) {
#pragma unroll
        for (int k = 0; k < KNN; ++k) { redw[wv][k] = s1[k]; redw[wv][16 + k] = s2[k]; }
    }
    __syncthreads();
#pragma unroll
    for (int k = 0; k < KNN; ++k) {
        float S1 = redw[0][k] + redw[1][k];
        float S2 = redw[0][16 + k] + redw[1][16 + k];
        float mu = S1 * (1.0f / HID);
        float var = S2 * (1.0f / HID) - mu * mu;
        float rstd = rsqrtf(var + 1e-5f);
        float xn = (h[k] - mu) * rstd * g1t + be1t;
        pm[k][tid] = gelu_t(xn);
    }
    __syncthreads();

    // ---- GEMM2: out2[k][o] = sum_t pm[k][t] * W2[t][o]; wave wv covers t half ----
    const int o = lane;
    const int tb = wv * 64;
    float a2[KNN];
#pragma unroll
    for (int k = 0; k < KNN; ++k) a2[k] = 0.0f;
#pragma unroll
    for (int t8 = 0; t8 < 64; t8 += 8) {
        uint4 wp = *(const uint4*)&w2h[o][tb + t8];
        float w0 = bl(wp.x), wA = bh(wp.x), w2v = bl(wp.y), w3 = bh(wp.y);
        float w4 = bl(wp.z), w5 = bh(wp.z), w6 = bl(wp.w), w7 = bh(wp.w);
#pragma unroll
        for (int k = 0; k < KNN; ++k) {
            float4 pa = *(const float4*)&pm[k][tb + t8];
            float4 pb = *(const float4*)&pm[k][tb + t8 + 4];
            a2[k] = fmaf(pa.x, w0, fmaf(pa.y, wA, fmaf(pa.z, w2v, fmaf(pa.w, w3,
                    fmaf(pb.x, w4, fmaf(pb.y, w5, fmaf(pb.z, w6, fmaf(pb.w, w7, a2[k]))))))));
        }
    }

    // ---- mean over K (+b2) -> msh[64]; partm overlays pm (pm fully consumed) ----
    float* partm = &pm[0][0];                 // [2][16][64] = 2048 floats < 16*132
    __syncthreads();
#pragma unroll
    for (int k = 0; k < KNN; ++k) partm[wv * 1024 + k * 64 + o] = a2[k];
    __syncthreads();
    if (tid < COUT) {
        float s = 0.0f;
#pragma unroll
        for (int k = 0; k < KNN; ++k) s += partm[k * 64 + tid] + partm[1024 + k * 64 + tid];
        msh[tid] = s * (1.0f / KNN) + b2[tid];
    }
    __syncthreads();

    // ---- point MLP: 64 -> 128 -> LN -> GELU -> 64 (weights from global/L2) ----
    float ho = bo1[tid];
#pragma unroll
    for (int c = 0; c < COUT; c += 4) {
        float4 mv = *(const float4*)&msh[c];
        ho = fmaf(mv.x, Wo1[(c + 0) * HID + tid], ho);
        ho = fmaf(mv.y, Wo1[(c + 1) * HID + tid], ho);
        ho = fmaf(mv.z, Wo1[(c + 2) * HID + tid], ho);
        ho = fmaf(mv.w, Wo1[(c + 3) * HID + tid], ho);
    }
    float t1 = ho, t2 = ho * ho;
#pragma unroll
    for (int off = 1; off < 64; off <<= 1) {
        t1 += __shfl_xor(t1, off, 64);
        t2 += __shfl_xor(t2, off, 64);
    }
    if (lane == 0) { redw[wv][0] = t1; redw[wv][1] = t2; }
    __syncthreads();
    {
        float S1 = redw[0][0] + redw[1][0];
        float S2 = redw[0][1] + redw[1][1];
        float mu = S1 * (1.0f / HID);
        float var = S2 * (1.0f / HID) - mu * mu;
        float rstd = rsqrtf(var + 1e-5f);
        float xo = (ho - mu) * rstd * go[tid] + beo[tid];
        float* ps = &em[0][0];               // reuse (em dead)
        ps[tid] = gelu_t(xo);
        __syncthreads();
        float p2 = 0.0f;
#pragma unroll
        for (int t4 = 0; t4 < 64; t4 += 4) {
            float4 pv = *(const float4*)&ps[tb + t4];
            p2 = fmaf(pv.x, Wo2[(tb + t4 + 0) * COUT + o], p2);
            p2 = fmaf(pv.y, Wo2[(tb + t4 + 1) * COUT + o], p2);
            p2 = fmaf(pv.z, Wo2[(tb + t4 + 2) * COUT + o], p2);
            p2 = fmaf(pv.w, Wo2[(tb + t4 + 3) * COUT + o], p2);
        }
        part2[wv][o] = p2;
    }
    __syncthreads();
    if (tid < COUT) out[(size_t)pt * COUT + tid] = part2[0][tid] + part2[1][tid] + bo2[tid];
}

extern "C" void kernel_launch(void* const* d_in, const int* in_sizes, int n_in,
                              void* d_out, int out_size, void* d_ws, size_t ws_size,
                              hipStream_t stream) {
    const float* verts = (const float*)d_in[0];
    const float* feats = (const float*)d_in[1];
    const float* W1  = (const float*)d_in[2];
    const float* b1  = (const float*)d_in[3];
    const float* g1  = (const float*)d_in[4];
    const float* be1 = (const float*)d_in[5];
    const float* W2  = (const float*)d_in[6];
    const float* b2  = (const float*)d_in[7];
    const float* Wo1 = (const float*)d_in[8];
    const float* bo1 = (const float*)d_in[9];
    const float* go  = (const float*)d_in[10];
    const float* beo = (const float*)d_in[11];
    const float* Wo2 = (const float*)d_in[12];
    const float* bo2 = (const float*)d_in[13];

    (void)in_sizes; (void)n_in; (void)d_ws; (void)ws_size; (void)out_size;

    knn_kernel<<<(BATCH * NPTS) / 4, 256, 0, stream>>>(verts, (int*)d_out);
    mlp_kernel<<<BATCH * NPTS, 128, 0, stream>>>(
        verts, feats, W1, b1, g1, be1, W2, b2,
        Wo1, bo1, go, beo, Wo2, bo2, (float*)d_out);
}

// Round 6
// 332.508 us; speedup vs baseline: 12.8792x; 2.7906x over previous
//
#include <hip/hip_runtime.h>
#include <hip/hip_bf16.h>
#include <math.h>

#define BATCH 2
#define NPTS  8192
#define CIN   32
#define HID   128
#define COUT  64
#define EIN   67
#define KNN   16

#define TILE  1024   // knn candidate tile
#define CAP   128    // knn survivor cap per wave

#define G      8                          // points per group (1 pt = 1 M-tile)
#define GROUPS 4
#define NBLK   (BATCH*NPTS/(G*GROUPS))    // 512 blocks

typedef unsigned short u16;
typedef unsigned long long u64;
typedef __attribute__((ext_vector_type(8))) short bf16x8;  // MFMA A/B frag
typedef __attribute__((ext_vector_type(4))) float f32x4;   // MFMA C/D frag

__device__ __forceinline__ u16 f2b(float f) {   // RNE fp32->bf16
    unsigned u = __float_as_uint(f);
    return (u16)((u + 0x7FFFu + ((u >> 16) & 1u)) >> 16);
}
__device__ __forceinline__ unsigned pk2(float a, float b) {
    return (unsigned)f2b(a) | ((unsigned)f2b(b) << 16);
}
__device__ __forceinline__ float gelu_t(float x) {
    float u = 1.5957691216057308f * (x + 0.044715f * x * x * x);
    float ex = __expf(u);
    return x * ex / (ex + 1.0f);
}

// ======================= KNN (unchanged from round 5) =======================
__global__ __launch_bounds__(256) void knn_kernel(const float* __restrict__ verts,
                                                  int* nbr_out_rows) {
    __shared__ float4 tilebuf[TILE];
    __shared__ float  bufD[4][CAP];
    __shared__ int    bufJ[4][CAP];

    const int tid = threadIdx.x, lane = tid & 63, wv = tid >> 6;
    const int pt = blockIdx.x * 4 + wv;
    const int b = pt >> 13, i = pt & (NPTS - 1);
    const float* vb = verts + (size_t)b * NPTS * 3;

    const float xi = vb[3 * i], yi = vb[3 * i + 1], zi = vb[3 * i + 2];
    const float sqi = xi * xi + yi * yi + zi * zi;

    float m_d = INFINITY; int m_j = 0;
    for (int t = 0; t < NPTS / TILE; ++t) {
        __syncthreads();
        for (int s = 0; s < TILE / 256; ++s) {
            int p = t * TILE + s * 256 + tid;
            float px = vb[3 * p], py = vb[3 * p + 1], pz = vb[3 * p + 2];
            tilebuf[s * 256 + tid] = make_float4(px, py, pz, px * px + py * py + pz * pz);
        }
        __syncthreads();
        for (int it = 0; it < TILE / 64; ++it) {
            int jl = it * 64 + lane;
            float4 c = tilebuf[jl];
            float d = (sqi + c.w) - 2.0f * (xi * c.x + yi * c.y + zi * c.z);
            if (d < m_d) { m_d = d; m_j = t * TILE + jl; }
        }
    }

    float pd = m_d; int pj = m_j;
    float tau = INFINITY;
    for (int r = 0; r < KNN; ++r) {
        float md = pd; int mj = pj;
#pragma unroll
        for (int off = 1; off < 64; off <<= 1) {
            float od = __shfl_xor(md, off, 64);
            int   oj = __shfl_xor(mj, off, 64);
            if (od < md || (od == md && oj < mj)) { md = od; mj = oj; }
        }
        tau = md;
        if (pj == mj && pd == md) { pd = INFINITY; pj = 0x7FFFFFFF; }
    }

    int base = 0;
    for (int t = 0; t < NPTS / TILE; ++t) {
        __syncthreads();
        for (int s = 0; s < TILE / 256; ++s) {
            int p = t * TILE + s * 256 + tid;
            float px = vb[3 * p], py = vb[3 * p + 1], pz = vb[3 * p + 2];
            tilebuf[s * 256 + tid] = make_float4(px, py, pz, px * px + py * py + pz * pz);
        }
        __syncthreads();
        for (int it = 0; it < TILE / 64; ++it) {
            int jl = it * 64 + lane;
            float4 c = tilebuf[jl];
            float d = (sqi + c.w) - 2.0f * (xi * c.x + yi * c.y + zi * c.z);
            bool pred = (d <= tau);
            u64 mask = __ballot(pred);
            if (pred) {
                int pos = base + __popcll(mask & ((1ull << lane) - 1ull));
                if (pos < CAP) { bufD[wv][pos] = d; bufJ[wv][pos] = t * TILE + jl; }
            }
            base += (int)__popcll(mask);
        }
    }
    int ns = (base > CAP) ? CAP : base;

    float d0 = (lane < ns)      ? bufD[wv][lane]      : INFINITY;
    int   j0 = (lane < ns)      ? bufJ[wv][lane]      : 0x7FFFFFFF;
    float d1 = (64 + lane < ns) ? bufD[wv][64 + lane] : INFINITY;
    int   j1 = (64 + lane < ns) ? bufJ[wv][64 + lane] : 0x7FFFFFFF;
    int myout = 0;
    for (int r = 0; r < KNN; ++r) {
        bool use0 = (d0 < d1) || (d0 == d1 && j0 < j1);
        float cd = use0 ? d0 : d1; int cj = use0 ? j0 : j1;
        float md = cd; int mj = cj;
#pragma unroll
        for (int off = 1; off < 64; off <<= 1) {
            float od = __shfl_xor(md, off, 64);
            int   oj = __shfl_xor(mj, off, 64);
            if (od < md || (od == md && oj < mj)) { md = od; mj = oj; }
        }
        if (lane == r) myout = mj;
        if (cj == mj && cd == md) {
            if (use0) { d0 = INFINITY; j0 = 0x7FFFFFFF; }
            else      { d1 = INFINITY; j1 = 0x7FFFFFFF; }
        }
    }
    if (lane < KNN) nbr_out_rows[pt * 64 + lane] = myout;
}

// ======================= MFMA edge MLP + mean =======================
// 256 thr / 4 waves; G=8 points per group, 1 point = 1 M-tile (its 16 edges).
// E gathered straight into A-frag layout; W1 B-frags in LDS; W2 B-frags in
// VGPRs. P (post-GELU) scatter-packed into A-frag layout overlaying E's slot.
__global__ __launch_bounds__(256, 2) void edge_kernel(
    const float* __restrict__ verts, const float* __restrict__ feats,
    const float* __restrict__ W1, const float* __restrict__ b1,
    const float* __restrict__ g1, const float* __restrict__ be1,
    const float* __restrict__ W2, const float* __restrict__ b2,
    float* out)   // rows hold knn idx on entry; mean (64 f32) on exit
{
    __shared__ u16 EP[G][4][64][8];     // 32 KB: E frags kt0..2; kt3 + reuse = P frags
    __shared__ u16 W1F[3][8][64][8];    // 24 KB: W1 B-frags [kt][nt][lane][8]
    __shared__ float b1s[HID], g1s[HID], be1s[HID];
    __shared__ float b2s[COUT];
    __shared__ int   nbrs[G][KNN];

    const int tid  = threadIdx.x;
    const int lane = tid & 63, wv = tid >> 6;
    const int quad = lane >> 4, n16 = lane & 15;

    // ---- stage W1 as B-fragments (once per block) ----
    for (int s = tid; s < 3 * 8 * 64; s += 256) {
        int kt = s >> 9, nt = (s >> 6) & 7, ln = s & 63;
        int q = ln >> 4, nn = ln & 15;
        int col = nt * 16 + nn;
        union { bf16x8 v; unsigned u[4]; } pk;
#pragma unroll
        for (int jj = 0; jj < 4; ++jj) {
            int k0 = kt * 32 + q * 8 + jj * 2;
            float a  = (k0     < EIN) ? W1[(size_t)k0 * HID + col]       : 0.0f;
            float bq = (k0 + 1 < EIN) ? W1[(size_t)(k0 + 1) * HID + col] : 0.0f;
            pk.u[jj] = pk2(a, bq);
        }
        *(bf16x8*)&W1F[kt][nt][ln][0] = pk.v;
    }
    if (tid < HID) { b1s[tid] = b1[tid]; g1s[tid] = g1[tid]; be1s[tid] = be1[tid]; }
    if (tid < COUT) b2s[tid] = b2[tid];

    // ---- stage W2 as B-fragments in registers (16 frags = 64 VGPR) ----
    bf16x8 w2r[4][4];
#pragma unroll
    for (int kt2 = 0; kt2 < 4; ++kt2)
#pragma unroll
        for (int nt2 = 0; nt2 < 4; ++nt2) {
            union { bf16x8 v; unsigned u[4]; } pk;
#pragma unroll
            for (int jj = 0; jj < 4; ++jj) {
                int k0 = kt2 * 32 + quad * 8 + jj * 2;
                int o = nt2 * 16 + n16;
                pk.u[jj] = pk2(W2[(size_t)k0 * COUT + o],
                               W2[(size_t)(k0 + 1) * COUT + o]);
            }
            w2r[kt2][nt2] = pk.v;
        }

    for (int g = 0; g < GROUPS; ++g) {
        const int P0 = (blockIdx.x * GROUPS + g) * G;   // global point id base
        const int bb = P0 >> 13;
        const float* fb  = feats + (size_t)bb * NPTS * CIN;
        const float* vbk = verts + (size_t)bb * NPTS * 3;

        __syncthreads();   // EP/nbrs free from previous group (and W1F staged)
        if (tid < G * KNN)
            nbrs[tid >> 4][tid & 15] =
                ((const int*)out)[(size_t)(P0 + (tid >> 4)) * 64 + (tid & 15)];
        __syncthreads();

        // ---- gather: edge m = p*16+k; chunk c8 covers channels c8*8..c8*8+7 ----
        {
            int m = tid & 127;
            int p = m >> 4, k = m & 15;
            int coff = tid >> 7;                 // 0 or 1
            int jn = nbrs[p][k];
            int ip = (P0 & (NPTS - 1)) + p;      // local point index
#pragma unroll
            for (int it = 0; it < 6; ++it) {
                int c8 = it * 2 + coff;          // 0..11
                union { bf16x8 v; unsigned u[4]; } pk;
                if (c8 < 4) {                    // neighbor feats c=0..31
                    const float* src = fb + (size_t)jn * CIN + c8 * 8;
                    float4 A = *(const float4*)src, B4 = *(const float4*)(src + 4);
                    pk.u[0] = pk2(A.x, A.y); pk.u[1] = pk2(A.z, A.w);
                    pk.u[2] = pk2(B4.x, B4.y); pk.u[3] = pk2(B4.z, B4.w);
                } else if (c8 < 8) {             // self feats c=32..63
                    const float* src = fb + (size_t)ip * CIN + (c8 - 4) * 8;
                    float4 A = *(const float4*)src, B4 = *(const float4*)(src + 4);
                    pk.u[0] = pk2(A.x, A.y); pk.u[1] = pk2(A.z, A.w);
                    pk.u[2] = pk2(B4.x, B4.y); pk.u[3] = pk2(B4.z, B4.w);
                } else if (c8 == 8) {            // rel pos c=64..66, pad
                    float dx = vbk[3 * jn]     - vbk[3 * ip];
                    float dy = vbk[3 * jn + 1] - vbk[3 * ip + 1];
                    float dz = vbk[3 * jn + 2] - vbk[3 * ip + 2];
                    pk.u[0] = pk2(dx, dy); pk.u[1] = pk2(dz, 0.0f);
                    pk.u[2] = 0u; pk.u[3] = 0u;
                } else {                         // zero pad c=72..95
                    pk.u[0] = pk.u[1] = pk.u[2] = pk.u[3] = 0u;
                }
                *(bf16x8*)&EP[p][c8 >> 2][k + 16 * (c8 & 3)][0] = pk.v;
            }
        }
        __syncthreads();

        // ---- per-wave M-tiles: mt = wv and wv+4 ----
#pragma unroll
        for (int half = 0; half < 2; ++half) {
            const int mt = wv + half * 4;        // == point p

            // GEMM1: D1[16 edges][128 hid]
            f32x4 acc[8];
#pragma unroll
            for (int nt = 0; nt < 8; ++nt) acc[nt] = (f32x4){0.f, 0.f, 0.f, 0.f};
#pragma unroll
            for (int kt = 0; kt < 3; ++kt) {
                bf16x8 a = *(bf16x8*)&EP[mt][kt][lane][0];
#pragma unroll
                for (int nt = 0; nt < 8; ++nt) {
                    bf16x8 bfr = *(bf16x8*)&W1F[kt][nt][lane][0];
                    acc[nt] = __builtin_amdgcn_mfma_f32_16x16x32_bf16(a, bfr, acc[nt], 0, 0, 0);
                }
            }

            // bias + LN stats (rows m = quad*4+reg; 16-lane group shuffles)
            float b1v[8], g1v[8], bev[8];
#pragma unroll
            for (int nt = 0; nt < 8; ++nt) {
                b1v[nt] = b1s[nt * 16 + n16];
                g1v[nt] = g1s[nt * 16 + n16];
                bev[nt] = be1s[nt * 16 + n16];
            }
            float s1[4] = {0,0,0,0}, s2[4] = {0,0,0,0};
#pragma unroll
            for (int nt = 0; nt < 8; ++nt)
#pragma unroll
                for (int r = 0; r < 4; ++r) {
                    float x = acc[nt][r] + b1v[nt];
                    s1[r] += x; s2[r] += x * x;
                }
#pragma unroll
            for (int r = 0; r < 4; ++r) {
#pragma unroll
                for (int off = 1; off < 16; off <<= 1) {
                    s1[r] += __shfl_xor(s1[r], off, 64);
                    s2[r] += __shfl_xor(s2[r], off, 64);
                }
            }
            float mu[4], rs[4];
#pragma unroll
            for (int r = 0; r < 4; ++r) {
                mu[r] = s1[r] * (1.0f / HID);
                float var = s2[r] * (1.0f / HID) - mu[r] * mu[r];
                rs[r] = rsqrtf(var + 1e-5f);
            }

            // GELU + pack bf16 + scatter into A-frag layout (P over EP[mt])
#pragma unroll
            for (int nt = 0; nt < 8; ++nt) {
                int kt2 = nt >> 1;
                int q2  = (nt * 2 + (n16 >> 3)) & 3;
                int jj  = n16 & 7;
#pragma unroll
                for (int r = 0; r < 4; ++r) {
                    float x  = acc[nt][r] + b1v[nt];
                    float xn = (x - mu[r]) * rs[r] * g1v[nt] + bev[nt];
                    EP[mt][kt2][quad * 4 + r + 16 * q2][jj] = (u16)f2b(gelu_t(xn));
                }
            }
            // same-wave LDS ops execute in order: P writes precede GEMM2 reads

            // GEMM2: D2[16 edges][64 out]
            f32x4 acc2[4];
#pragma unroll
            for (int nt2 = 0; nt2 < 4; ++nt2) acc2[nt2] = (f32x4){0.f, 0.f, 0.f, 0.f};
#pragma unroll
            for (int kt2 = 0; kt2 < 4; ++kt2) {
                bf16x8 a2 = *(bf16x8*)&EP[mt][kt2][lane][0];
#pragma unroll
                for (int nt2 = 0; nt2 < 4; ++nt2)
                    acc2[nt2] = __builtin_amdgcn_mfma_f32_16x16x32_bf16(a2, w2r[kt2][nt2], acc2[nt2], 0, 0, 0);
            }

            // mean over 16 edges (+b2) -> out row (fp32)
#pragma unroll
            for (int nt2 = 0; nt2 < 4; ++nt2) {
                float cs = acc2[nt2][0] + acc2[nt2][1] + acc2[nt2][2] + acc2[nt2][3];
                cs += __shfl_xor(cs, 16, 64);
                cs += __shfl_xor(cs, 32, 64);
                if (quad == 0) {
                    int o = nt2 * 16 + n16;
                    out[(size_t)(P0 + mt) * 64 + o] = cs * (1.0f / KNN) + b2s[o];
                }
            }
        }
    }
}

// ======================= point MLP (fp32, standalone) =======================
__device__ __forceinline__ void ln_stats(float h, float* red, int tid,
                                         float& mu, float& rstd) {
    int lane = tid & 63, wvv = tid >> 6;
    float s1 = h, s2 = h * h;
#pragma unroll
    for (int off = 1; off < 64; off <<= 1) {
        s1 += __shfl_xor(s1, off, 64);
        s2 += __shfl_xor(s2, off, 64);
    }
    __syncthreads();
    if (lane == 0) { red[wvv * 2] = s1; red[wvv * 2 + 1] = s2; }
    __syncthreads();
    float S1 = red[0] + red[2];
    float S2 = red[1] + red[3];
    mu = S1 * (1.0f / HID);
    float var = S2 * (1.0f / HID) - mu * mu;
    rstd = rsqrtf(var + 1e-5f);
}

__global__ __launch_bounds__(128) void point_kernel(
    const float* __restrict__ Wo1, const float* __restrict__ bo1,
    const float* __restrict__ go, const float* __restrict__ beo,
    const float* __restrict__ Wo2, const float* __restrict__ bo2,
    float* out)
{
    __shared__ float msh[COUT];
    __shared__ float gh[HID];
    __shared__ float red[4];
    __shared__ float part[HID];

    const int tid = threadIdx.x, wvv = tid >> 6;
    const int pt = blockIdx.x;

    if (tid < COUT) msh[tid] = out[(size_t)pt * 64 + tid];
    __syncthreads();

    float ho = bo1[tid];
#pragma unroll
    for (int c = 0; c < COUT; c += 4) {
        float4 mv = *(const float4*)&msh[c];
        ho = fmaf(mv.x, Wo1[(c + 0) * HID + tid], ho);
        ho = fmaf(mv.y, Wo1[(c + 1) * HID + tid], ho);
        ho = fmaf(mv.z, Wo1[(c + 2) * HID + tid], ho);
        ho = fmaf(mv.w, Wo1[(c + 3) * HID + tid], ho);
    }
    float mu, rstd;
    ln_stats(ho, red, tid, mu, rstd);
    float xo = (ho - mu) * rstd * go[tid] + beo[tid];
    gh[tid] = gelu_t(xo);
    __syncthreads();

    const int o = tid & 63, tb = wvv * 64;
    float p2 = 0.0f;
#pragma unroll
    for (int t4 = 0; t4 < 64; t4 += 4) {
        float4 pv = *(const float4*)&gh[tb + t4];
        p2 = fmaf(pv.x, Wo2[(tb + t4 + 0) * COUT + o], p2);
        p2 = fmaf(pv.y, Wo2[(tb + t4 + 1) * COUT + o], p2);
        p2 = fmaf(pv.z, Wo2[(tb + t4 + 2) * COUT + o], p2);
        p2 = fmaf(pv.w, Wo2[(tb + t4 + 3) * COUT + o], p2);
    }
    part[tid] = p2;
    __syncthreads();
    if (tid < COUT) out[(size_t)pt * 64 + tid] = part[tid] + part[64 + tid] + bo2[tid];
}

extern "C" void kernel_launch(void* const* d_in, const int* in_sizes, int n_in,
                              void* d_out, int out_size, void* d_ws, size_t ws_size,
                              hipStream_t stream) {
    const float* verts = (const float*)d_in[0];
    const float* feats = (const float*)d_in[1];
    const float* W1  = (const float*)d_in[2];
    const float* b1  = (const float*)d_in[3];
    const float* g1  = (const float*)d_in[4];
    const float* be1 = (const float*)d_in[5];
    const float* W2  = (const float*)d_in[6];
    const float* b2  = (const float*)d_in[7];
    const float* Wo1 = (const float*)d_in[8];
    const float* bo1 = (const float*)d_in[9];
    const float* go  = (const float*)d_in[10];
    const float* beo = (const float*)d_in[11];
    const float* Wo2 = (const float*)d_in[12];
    const float* bo2 = (const float*)d_in[13];
    float* out = (float*)d_out;

    (void)in_sizes; (void)n_in; (void)d_ws; (void)ws_size; (void)out_size;

    knn_kernel<<<(BATCH * NPTS) / 4, 256, 0, stream>>>(verts, (int*)out);
    edge_kernel<<<NBLK, 256, 0, stream>>>(verts, feats, W1, b1, g1, be1, W2, b2, out);
    point_kernel<<<BATCH * NPTS, 128, 0, stream>>>(Wo1, bo1, go, beo, Wo2, bo2, out);
}

// Round 7
// 301.431 us; speedup vs baseline: 14.2070x; 1.1031x over previous
//
#include <hip/hip_runtime.h>
#include <hip/hip_bf16.h>
#include <math.h>

#define BATCH 2
#define NPTS  8192
#define CIN   32
#define HID   128
#define COUT  64
#define EIN   67
#define KNN   16

#define TILE  1024   // fallback knn candidate tile
#define CAP   128    // knn survivor cap per wave

#define G      8                          // points per group (1 pt = 1 M-tile)
#define GROUPS 4
#define NBLK   (BATCH*NPTS/(G*GROUPS))    // 512 blocks

typedef unsigned short u16;
typedef unsigned long long u64;
typedef __attribute__((ext_vector_type(8))) short bf16x8;  // MFMA A/B frag
typedef __attribute__((ext_vector_type(4))) float f32x4;   // MFMA C/D frag

__device__ __forceinline__ u16 f2b(float f) {   // RNE fp32->bf16
    unsigned u = __float_as_uint(f);
    return (u16)((u + 0x7FFFu + ((u >> 16) & 1u)) >> 16);
}
__device__ __forceinline__ unsigned pk2(float a, float b) {
    return (unsigned)f2b(a) | ((unsigned)f2b(b) << 16);
}
__device__ __forceinline__ float gelu_t(float x) {
    float u = 1.5957691216057308f * (x + 0.044715f * x * x * x);
    float ex = __expf(u);
    return x * ex / (ex + 1.0f);
}

// ============== prep: verts -> float4 {x,y,z,sq} in d_ws ==============
__global__ void prep_kernel(const float* __restrict__ verts, float4* __restrict__ pv) {
    int i = blockIdx.x * blockDim.x + threadIdx.x;
    if (i >= BATCH * NPTS) return;
    float x = verts[3 * i], y = verts[3 * i + 1], z = verts[3 * i + 2];
    float sq = __fadd_rn(__fadd_rn(__fmul_rn(x, x), __fmul_rn(y, y)), __fmul_rn(z, z));
    pv[i] = make_float4(x, y, z, sq);
}

// ============== KNN v2: pv-based, rank-select merges ==============
// 1 wave per point, 4 waves/block. Pass 1: pure value-min per lane.
// tau = 16th-smallest lane-min (rank-select). Pass 2: ballot-compact
// survivors (d <= tau), then lex-rank (d,j) < 16 -> output slot = rank.
__global__ __launch_bounds__(256) void knn2_kernel(const float4* __restrict__ pv,
                                                   int* __restrict__ nbr_out_rows) {
    __shared__ float minv[4][64];
    __shared__ float bufD[4][CAP];
    __shared__ int   bufJ[4][CAP];

    const int tid = threadIdx.x, lane = tid & 63, wv = tid >> 6;
    const int pt = blockIdx.x * 4 + wv;
    const int b = pt >> 13, i = pt & (NPTS - 1);
    const float4* P = pv + (size_t)b * NPTS;

    float4 s = P[i];
    const float xi = s.x, yi = s.y, zi = s.z, sqi = s.w;

    // ---- pass 1: per-lane min over 128 candidates ----
    float m_d = INFINITY;
#pragma unroll 8
    for (int t = 0; t < NPTS / 64; ++t) {
        float4 c = P[t * 64 + lane];
        float dot = __fmul_rn(xi, c.x);
        dot = __fmaf_rn(yi, c.y, dot);
        dot = __fmaf_rn(zi, c.z, dot);
        float d = __fsub_rn(__fadd_rn(sqi, c.w), __fmul_rn(2.0f, dot));
        m_d = fminf(m_d, d);
    }

    // ---- tau = 16th smallest of the 64 lane minima (rank-select) ----
    minv[wv][lane] = m_d;
    __syncthreads();
    int rnk = 0;
    for (int mm = 0; mm < 64; ++mm) {
        float vm = minv[wv][mm];
        rnk += (vm < m_d) || (vm == m_d && mm < lane);
    }
    u64 bal = __ballot(rnk == 15);
    int srcl = __ffsll(bal) - 1;
    float tau = __shfl(m_d, srcl, 64);

    // ---- pass 2: ballot-compact survivors d <= tau ----
    int base = 0;
    for (int t = 0; t < NPTS / 64; ++t) {
        int j = t * 64 + lane;
        float4 c = P[j];
        float dot = __fmul_rn(xi, c.x);
        dot = __fmaf_rn(yi, c.y, dot);
        dot = __fmaf_rn(zi, c.z, dot);
        float d = __fsub_rn(__fadd_rn(sqi, c.w), __fmul_rn(2.0f, dot));
        bool pred = (d <= tau);
        u64 mask = __ballot(pred);
        if (pred) {
            int pos = base + __popcll(mask & ((1ull << lane) - 1ull));
            if (pos < CAP) { bufD[wv][pos] = d; bufJ[wv][pos] = j; }
        }
        base += (int)__popcll(mask);
    }
    int ns = (base > CAP) ? CAP : base;   // >= 16 guaranteed
    __syncthreads();

    // ---- exact top-16: lex-rank (d,j) among survivors; slot = rank ----
#pragma unroll
    for (int slot = 0; slot < 2; ++slot) {
        int sidx = slot * 64 + lane;
        if (sidx < ns) {
            float ds = bufD[wv][sidx];
            int   js = bufJ[wv][sidx];
            int rank = 0;
            for (int mm = 0; mm < ns; ++mm) {
                float dm = bufD[wv][mm];
                int   jm = bufJ[wv][mm];
                rank += (dm < ds) || (dm == ds && jm < js);
            }
            if (rank < KNN) nbr_out_rows[(size_t)pt * 64 + rank] = js;
        }
    }
}

// ============== KNN fallback (round-6 version, used if ws too small) ==============
__global__ __launch_bounds__(256) void knn_kernel(const float* __restrict__ verts,
                                                  int* nbr_out_rows) {
    __shared__ float4 tilebuf[TILE];
    __shared__ float  bufD[4][CAP];
    __shared__ int    bufJ[4][CAP];

    const int tid = threadIdx.x, lane = tid & 63, wv = tid >> 6;
    const int pt = blockIdx.x * 4 + wv;
    const int b = pt >> 13, i = pt & (NPTS - 1);
    const float* vb = verts + (size_t)b * NPTS * 3;

    const float xi = vb[3 * i], yi = vb[3 * i + 1], zi = vb[3 * i + 2];
    const float sqi = __fadd_rn(__fadd_rn(__fmul_rn(xi, xi), __fmul_rn(yi, yi)),
                                __fmul_rn(zi, zi));

    float m_d = INFINITY; int m_j = 0;
    for (int t = 0; t < NPTS / TILE; ++t) {
        __syncthreads();
        for (int s = 0; s < TILE / 256; ++s) {
            int p = t * TILE + s * 256 + tid;
            float px = vb[3 * p], py = vb[3 * p + 1], pz = vb[3 * p + 2];
            float sq = __fadd_rn(__fadd_rn(__fmul_rn(px, px), __fmul_rn(py, py)),
                                 __fmul_rn(pz, pz));
            tilebuf[s * 256 + tid] = make_float4(px, py, pz, sq);
        }
        __syncthreads();
        for (int it = 0; it < TILE / 64; ++it) {
            int jl = it * 64 + lane;
            float4 c = tilebuf[jl];
            float dot = __fmul_rn(xi, c.x);
            dot = __fmaf_rn(yi, c.y, dot);
            dot = __fmaf_rn(zi, c.z, dot);
            float d = __fsub_rn(__fadd_rn(sqi, c.w), __fmul_rn(2.0f, dot));
            if (d < m_d) { m_d = d; m_j = t * TILE + jl; }
        }
    }

    float pd = m_d; int pj = m_j;
    float tau = INFINITY;
    for (int r = 0; r < KNN; ++r) {
        float md = pd; int mj = pj;
#pragma unroll
        for (int off = 1; off < 64; off <<= 1) {
            float od = __shfl_xor(md, off, 64);
            int   oj = __shfl_xor(mj, off, 64);
            if (od < md || (od == md && oj < mj)) { md = od; mj = oj; }
        }
        tau = md;
        if (pj == mj && pd == md) { pd = INFINITY; pj = 0x7FFFFFFF; }
    }

    int base = 0;
    for (int t = 0; t < NPTS / TILE; ++t) {
        __syncthreads();
        for (int s = 0; s < TILE / 256; ++s) {
            int p = t * TILE + s * 256 + tid;
            float px = vb[3 * p], py = vb[3 * p + 1], pz = vb[3 * p + 2];
            float sq = __fadd_rn(__fadd_rn(__fmul_rn(px, px), __fmul_rn(py, py)),
                                 __fmul_rn(pz, pz));
            tilebuf[s * 256 + tid] = make_float4(px, py, pz, sq);
        }
        __syncthreads();
        for (int it = 0; it < TILE / 64; ++it) {
            int jl = it * 64 + lane;
            float4 c = tilebuf[jl];
            float dot = __fmul_rn(xi, c.x);
            dot = __fmaf_rn(yi, c.y, dot);
            dot = __fmaf_rn(zi, c.z, dot);
            float d = __fsub_rn(__fadd_rn(sqi, c.w), __fmul_rn(2.0f, dot));
            bool pred = (d <= tau);
            u64 mask = __ballot(pred);
            if (pred) {
                int pos = base + __popcll(mask & ((1ull << lane) - 1ull));
                if (pos < CAP) { bufD[wv][pos] = d; bufJ[wv][pos] = t * TILE + jl; }
            }
            base += (int)__popcll(mask);
        }
    }
    int ns = (base > CAP) ? CAP : base;
    __syncthreads();

#pragma unroll
    for (int slot = 0; slot < 2; ++slot) {
        int sidx = slot * 64 + lane;
        if (sidx < ns) {
            float ds = bufD[wv][sidx];
            int   js = bufJ[wv][sidx];
            int rank = 0;
            for (int mm = 0; mm < ns; ++mm) {
                float dm = bufD[wv][mm];
                int   jm = bufJ[wv][mm];
                rank += (dm < ds) || (dm == ds && jm < js);
            }
            if (rank < KNN) nbr_out_rows[(size_t)pt * 64 + rank] = js;
        }
    }
}

// ======================= MFMA edge MLP + mean (unchanged) =======================
__global__ __launch_bounds__(256, 2) void edge_kernel(
    const float* __restrict__ verts, const float* __restrict__ feats,
    const float* __restrict__ W1, const float* __restrict__ b1,
    const float* __restrict__ g1, const float* __restrict__ be1,
    const float* __restrict__ W2, const float* __restrict__ b2,
    float* out)   // rows hold knn idx on entry; mean (64 f32) on exit
{
    __shared__ u16 EP[G][4][64][8];
    __shared__ u16 W1F[3][8][64][8];
    __shared__ float b1s[HID], g1s[HID], be1s[HID];
    __shared__ float b2s[COUT];
    __shared__ int   nbrs[G][KNN];

    const int tid  = threadIdx.x;
    const int lane = tid & 63, wv = tid >> 6;
    const int quad = lane >> 4, n16 = lane & 15;

    for (int s = tid; s < 3 * 8 * 64; s += 256) {
        int kt = s >> 9, nt = (s >> 6) & 7, ln = s & 63;
        int q = ln >> 4, nn = ln & 15;
        int col = nt * 16 + nn;
        union { bf16x8 v; unsigned u[4]; } pk;
#pragma unroll
        for (int jj = 0; jj < 4; ++jj) {
            int k0 = kt * 32 + q * 8 + jj * 2;
            float a  = (k0     < EIN) ? W1[(size_t)k0 * HID + col]       : 0.0f;
            float bq = (k0 + 1 < EIN) ? W1[(size_t)(k0 + 1) * HID + col] : 0.0f;
            pk.u[jj] = pk2(a, bq);
        }
        *(bf16x8*)&W1F[kt][nt][ln][0] = pk.v;
    }
    if (tid < HID) { b1s[tid] = b1[tid]; g1s[tid] = g1[tid]; be1s[tid] = be1[tid]; }
    if (tid < COUT) b2s[tid] = b2[tid];

    bf16x8 w2r[4][4];
#pragma unroll
    for (int kt2 = 0; kt2 < 4; ++kt2)
#pragma unroll
        for (int nt2 = 0; nt2 < 4; ++nt2) {
            union { bf16x8 v; unsigned u[4]; } pk;
#pragma unroll
            for (int jj = 0; jj < 4; ++jj) {
                int k0 = kt2 * 32 + quad * 8 + jj * 2;
                int o = nt2 * 16 + n16;
                pk.u[jj] = pk2(W2[(size_t)k0 * COUT + o],
                               W2[(size_t)(k0 + 1) * COUT + o]);
            }
            w2r[kt2][nt2] = pk.v;
        }

    for (int g = 0; g < GROUPS; ++g) {
        const int P0 = (blockIdx.x * GROUPS + g) * G;
        const int bb = P0 >> 13;
        const float* fb  = feats + (size_t)bb * NPTS * CIN;
        const float* vbk = verts + (size_t)bb * NPTS * 3;

        __syncthreads();
        if (tid < G * KNN)
            nbrs[tid >> 4][tid & 15] =
                ((const int*)out)[(size_t)(P0 + (tid >> 4)) * 64 + (tid & 15)];
        __syncthreads();

        {
            int m = tid & 127;
            int p = m >> 4, k = m & 15;
            int coff = tid >> 7;
            int jn = nbrs[p][k];
            int ip = (P0 & (NPTS - 1)) + p;
#pragma unroll
            for (int it = 0; it < 6; ++it) {
                int c8 = it * 2 + coff;
                union { bf16x8 v; unsigned u[4]; } pk;
                if (c8 < 4) {
                    const float* src = fb + (size_t)jn * CIN + c8 * 8;
                    float4 A = *(const float4*)src, B4 = *(const float4*)(src + 4);
                    pk.u[0] = pk2(A.x, A.y); pk.u[1] = pk2(A.z, A.w);
                    pk.u[2] = pk2(B4.x, B4.y); pk.u[3] = pk2(B4.z, B4.w);
                } else if (c8 < 8) {
                    const float* src = fb + (size_t)ip * CIN + (c8 - 4) * 8;
                    float4 A = *(const float4*)src, B4 = *(const float4*)(src + 4);
                    pk.u[0] = pk2(A.x, A.y); pk.u[1] = pk2(A.z, A.w);
                    pk.u[2] = pk2(B4.x, B4.y); pk.u[3] = pk2(B4.z, B4.w);
                } else if (c8 == 8) {
                    float dx = vbk[3 * jn]     - vbk[3 * ip];
                    float dy = vbk[3 * jn + 1] - vbk[3 * ip + 1];
                    float dz = vbk[3 * jn + 2] - vbk[3 * ip + 2];
                    pk.u[0] = pk2(dx, dy); pk.u[1] = pk2(dz, 0.0f);
                    pk.u[2] = 0u; pk.u[3] = 0u;
                } else {
                    pk.u[0] = pk.u[1] = pk.u[2] = pk.u[3] = 0u;
                }
                *(bf16x8*)&EP[p][c8 >> 2][k + 16 * (c8 & 3)][0] = pk.v;
            }
        }
        __syncthreads();

#pragma unroll
        for (int half = 0; half < 2; ++half) {
            const int mt = wv + half * 4;

            f32x4 acc[8];
#pragma unroll
            for (int nt = 0; nt < 8; ++nt) acc[nt] = (f32x4){0.f, 0.f, 0.f, 0.f};
#pragma unroll
            for (int kt = 0; kt < 3; ++kt) {
                bf16x8 a = *(bf16x8*)&EP[mt][kt][lane][0];
#pragma unroll
                for (int nt = 0; nt < 8; ++nt) {
                    bf16x8 bfr = *(bf16x8*)&W1F[kt][nt][lane][0];
                    acc[nt] = __builtin_amdgcn_mfma_f32_16x16x32_bf16(a, bfr, acc[nt], 0, 0, 0);
                }
            }

            float b1v[8], g1v[8], bev[8];
#pragma unroll
            for (int nt = 0; nt < 8; ++nt) {
                b1v[nt] = b1s[nt * 16 + n16];
                g1v[nt] = g1s[nt * 16 + n16];
                bev[nt] = be1s[nt * 16 + n16];
            }
            float s1[4] = {0,0,0,0}, s2[4] = {0,0,0,0};
#pragma unroll
            for (int nt = 0; nt < 8; ++nt)
#pragma unroll
                for (int r = 0; r < 4; ++r) {
                    float x = acc[nt][r] + b1v[nt];
                    s1[r] += x; s2[r] += x * x;
                }
#pragma unroll
            for (int r = 0; r < 4; ++r) {
#pragma unroll
                for (int off = 1; off < 16; off <<= 1) {
                    s1[r] += __shfl_xor(s1[r], off, 64);
                    s2[r] += __shfl_xor(s2[r], off, 64);
                }
            }
            float mu[4], rs[4];
#pragma unroll
            for (int r = 0; r < 4; ++r) {
                mu[r] = s1[r] * (1.0f / HID);
                float var = s2[r] * (1.0f / HID) - mu[r] * mu[r];
                rs[r] = rsqrtf(var + 1e-5f);
            }

#pragma unroll
            for (int nt = 0; nt < 8; ++nt) {
                int kt2 = nt >> 1;
                int q2  = (nt * 2 + (n16 >> 3)) & 3;
                int jj  = n16 & 7;
#pragma unroll
                for (int r = 0; r < 4; ++r) {
                    float x  = acc[nt][r] + b1v[nt];
                    float xn = (x - mu[r]) * rs[r] * g1v[nt] + bev[nt];
                    EP[mt][kt2][quad * 4 + r + 16 * q2][jj] = (u16)f2b(gelu_t(xn));
                }
            }

            f32x4 acc2[4];
#pragma unroll
            for (int nt2 = 0; nt2 < 4; ++nt2) acc2[nt2] = (f32x4){0.f, 0.f, 0.f, 0.f};
#pragma unroll
            for (int kt2 = 0; kt2 < 4; ++kt2) {
                bf16x8 a2 = *(bf16x8*)&EP[mt][kt2][lane][0];
#pragma unroll
                for (int nt2 = 0; nt2 < 4; ++nt2)
                    acc2[nt2] = __builtin_amdgcn_mfma_f32_16x16x32_bf16(a2, w2r[kt2][nt2], acc2[nt2], 0, 0, 0);
            }

#pragma unroll
            for (int nt2 = 0; nt2 < 4; ++nt2) {
                float cs = acc2[nt2][0] + acc2[nt2][1] + acc2[nt2][2] + acc2[nt2][3];
                cs += __shfl_xor(cs, 16, 64);
                cs += __shfl_xor(cs, 32, 64);
                if (quad == 0) {
                    int o = nt2 * 16 + n16;
                    out[(size_t)(P0 + mt) * 64 + o] = cs * (1.0f / KNN) + b2s[o];
                }
            }
        }
    }
}

// ======================= point MLP (unchanged) =======================
__device__ __forceinline__ void ln_stats(float h, float* red, int tid,
                                         float& mu, float& rstd) {
    int lane = tid & 63, wvv = tid >> 6;
    float s1 = h, s2 = h * h;
#pragma unroll
    for (int off = 1; off < 64; off <<= 1) {
        s1 += __shfl_xor(s1, off, 64);
        s2 += __shfl_xor(s2, off, 64);
    }
    __syncthreads();
    if (lane == 0) { red[wvv * 2] = s1; red[wvv * 2 + 1] = s2; }
    __syncthreads();
    float S1 = red[0] + red[2];
    float S2 = red[1] + red[3];
    mu = S1 * (1.0f / HID);
    float var = S2 * (1.0f / HID) - mu * mu;
    rstd = rsqrtf(var + 1e-5f);
}

__global__ __launch_bounds__(128) void point_kernel(
    const float* __restrict__ Wo1, const float* __restrict__ bo1,
    const float* __restrict__ go, const float* __restrict__ beo,
    const float* __restrict__ Wo2, const float* __restrict__ bo2,
    float* out)
{
    __shared__ float msh[COUT];
    __shared__ float gh[HID];
    __shared__ float red[4];
    __shared__ float part[HID];

    const int tid = threadIdx.x, wvv = tid >> 6;
    const int pt = blockIdx.x;

    if (tid < COUT) msh[tid] = out[(size_t)pt * 64 + tid];
    __syncthreads();

    float ho = bo1[tid];
#pragma unroll
    for (int c = 0; c < COUT; c += 4) {
        float4 mv = *(const float4*)&msh[c];
        ho = fmaf(mv.x, Wo1[(c + 0) * HID + tid], ho);
        ho = fmaf(mv.y, Wo1[(c + 1) * HID + tid], ho);
        ho = fmaf(mv.z, Wo1[(c + 2) * HID + tid], ho);
        ho = fmaf(mv.w, Wo1[(c + 3) * HID + tid], ho);
    }
    float mu, rstd;
    ln_stats(ho, red, tid, mu, rstd);
    float xo = (ho - mu) * rstd * go[tid] + beo[tid];
    gh[tid] = gelu_t(xo);
    __syncthreads();

    const int o = tid & 63, tb = wvv * 64;
    float p2 = 0.0f;
#pragma unroll
    for (int t4 = 0; t4 < 64; t4 += 4) {
        float4 pv4 = *(const float4*)&gh[tb + t4];
        p2 = fmaf(pv4.x, Wo2[(tb + t4 + 0) * COUT + o], p2);
        p2 = fmaf(pv4.y, Wo2[(tb + t4 + 1) * COUT + o], p2);
        p2 = fmaf(pv4.z, Wo2[(tb + t4 + 2) * COUT + o], p2);
        p2 = fmaf(pv4.w, Wo2[(tb + t4 + 3) * COUT + o], p2);
    }
    part[tid] = p2;
    __syncthreads();
    if (tid < COUT) out[(size_t)pt * 64 + tid] = part[tid] + part[64 + tid] + bo2[tid];
}

extern "C" void kernel_launch(void* const* d_in, const int* in_sizes, int n_in,
                              void* d_out, int out_size, void* d_ws, size_t ws_size,
                              hipStream_t stream) {
    const float* verts = (const float*)d_in[0];
    const float* feats = (const float*)d_in[1];
    const float* W1  = (const float*)d_in[2];
    const float* b1  = (const float*)d_in[3];
    const float* g1  = (const float*)d_in[4];
    const float* be1 = (const float*)d_in[5];
    const float* W2  = (const float*)d_in[6];
    const float* b2  = (const float*)d_in[7];
    const float* Wo1 = (const float*)d_in[8];
    const float* bo1 = (const float*)d_in[9];
    const float* go  = (const float*)d_in[10];
    const float* beo = (const float*)d_in[11];
    const float* Wo2 = (const float*)d_in[12];
    const float* bo2 = (const float*)d_in[13];
    float* out = (float*)d_out;

    (void)in_sizes; (void)n_in; (void)out_size;

    const size_t pv_bytes = (size_t)BATCH * NPTS * sizeof(float4);  // 256 KB
    if (ws_size >= pv_bytes) {
        float4* pv = (float4*)d_ws;
        prep_kernel<<<(BATCH * NPTS + 255) / 256, 256, 0, stream>>>(verts, pv);
        knn2_kernel<<<(BATCH * NPTS) / 4, 256, 0, stream>>>(pv, (int*)out);
    } else {
        knn_kernel<<<(BATCH * NPTS) / 4, 256, 0, stream>>>(verts, (int*)out);
    }
    edge_kernel<<<NBLK, 256, 0, stream>>>(verts, feats, W1, b1, g1, be1, W2, b2, out);
    point_kernel<<<BATCH * NPTS, 128, 0, stream>>>(Wo1, bo1, go, beo, Wo2, bo2, out);
}

// Round 8
// 228.963 us; speedup vs baseline: 18.7036x; 1.3165x over previous
//
#include <hip/hip_runtime.h>
#include <hip/hip_bf16.h>
#include <math.h>

#define BATCH 2
#define NPTS  8192
#define CIN   32
#define HID   128
#define COUT  64
#define EIN   67
#define KNN   16

#define TILE  1024   // fallback knn candidate tile
#define CAP   128    // survivor cap per wave (fallback)
#define CAP2  128    // survivor cap per point (knn3)

#define G      8                          // points per group (1 pt = 1 M-tile)
#define GROUPS 4
#define NBLK   (BATCH*NPTS/(G*GROUPS))    // 512 blocks

typedef unsigned short u16;
typedef unsigned long long u64;
typedef __attribute__((ext_vector_type(8))) short bf16x8;  // MFMA A/B frag
typedef __attribute__((ext_vector_type(4))) float f32x4;   // MFMA C/D frag

__device__ __forceinline__ u16 f2b(float f) {   // RNE fp32->bf16
    unsigned u = __float_as_uint(f);
    return (u16)((u + 0x7FFFu + ((u >> 16) & 1u)) >> 16);
}
__device__ __forceinline__ unsigned pk2(float a, float b) {
    return (unsigned)f2b(a) | ((unsigned)f2b(b) << 16);
}
__device__ __forceinline__ float gelu_t(float x) {
    float u = 1.5957691216057308f * (x + 0.044715f * x * x * x);
    float ex = __expf(u);
    return x * ex / (ex + 1.0f);
}

// ============== prep: verts -> float4 {x,y,z,sq} in d_ws ==============
__global__ void prep_kernel(const float* __restrict__ verts, float4* __restrict__ pv) {
    int i = blockIdx.x * blockDim.x + threadIdx.x;
    if (i >= BATCH * NPTS) return;
    float x = verts[3 * i], y = verts[3 * i + 1], z = verts[3 * i + 2];
    float sq = __fadd_rn(__fadd_rn(__fmul_rn(x, x), __fmul_rn(y, y)), __fmul_rn(z, z));
    pv[i] = make_float4(x, y, z, sq);
}

// ============== KNN v3: 4 points/wave, half-sample tau ==============
// Pass 1: per-lane value-min over the FIRST 4096 candidates only — tau =
// 16th smallest lane-min over any candidate subset is a valid upper bound
// on d_(16) over the full set (16 distinct candidates <= tau), just looser
// (expected survivors ~32 << CAP2). Pass 2: full scan, exact d, compact.
__global__ __launch_bounds__(256, 4) void knn3_kernel(const float4* __restrict__ pv,
                                                      int* __restrict__ nbr_out_rows) {
    __shared__ float4 minv4[4][64];
    __shared__ float bufD[4][4][CAP2];
    __shared__ int   bufJ[4][4][CAP2];

    const int tid = threadIdx.x, lane = tid & 63, wv = tid >> 6;
    const int pt0 = (blockIdx.x * 4 + wv) * 4;       // 4 consecutive points
    const int b = pt0 >> 13, i0 = pt0 & (NPTS - 1);
    const float4* P = pv + (size_t)b * NPTS;

    float4 sp[4];
#pragma unroll
    for (int p = 0; p < 4; ++p) sp[p] = P[i0 + p];

    // ---- pass 1: per-lane min over first-half candidates, 4 points ----
    float mn[4] = {INFINITY, INFINITY, INFINITY, INFINITY};
#pragma unroll 4
    for (int t = 0; t < 64; ++t) {
        float4 c = P[t * 64 + lane];
#pragma unroll
        for (int p = 0; p < 4; ++p) {
            float dot = __fmul_rn(sp[p].x, c.x);
            dot = __fmaf_rn(sp[p].y, c.y, dot);
            dot = __fmaf_rn(sp[p].z, c.z, dot);
            float d = __fsub_rn(__fadd_rn(sp[p].w, c.w), __fmul_rn(2.0f, dot));
            mn[p] = fminf(mn[p], d);
        }
    }

    // ---- tau_p = 16th smallest of the 64 lane minima (rank-select) ----
    minv4[wv][lane] = make_float4(mn[0], mn[1], mn[2], mn[3]);
    __syncthreads();
    int rk[4] = {0, 0, 0, 0};
    for (int mm = 0; mm < 64; ++mm) {
        float4 v = minv4[wv][mm];
        rk[0] += (v.x < mn[0]) || (v.x == mn[0] && mm < lane);
        rk[1] += (v.y < mn[1]) || (v.y == mn[1] && mm < lane);
        rk[2] += (v.z < mn[2]) || (v.z == mn[2] && mm < lane);
        rk[3] += (v.w < mn[3]) || (v.w == mn[3] && mm < lane);
    }
    float tau[4];
#pragma unroll
    for (int p = 0; p < 4; ++p) {
        u64 bal = __ballot(rk[p] == 15);
        int srcl = __ffsll(bal) - 1;
        tau[p] = __shfl(mn[p], srcl, 64);
    }

    // ---- pass 2: full scan, ballot-compact survivors d <= tau_p ----
    int base[4] = {0, 0, 0, 0};
#pragma unroll 2
    for (int t = 0; t < 128; ++t) {
        float4 c = P[t * 64 + lane];
        int j = t * 64 + lane;
#pragma unroll
        for (int p = 0; p < 4; ++p) {
            float dot = __fmul_rn(sp[p].x, c.x);
            dot = __fmaf_rn(sp[p].y, c.y, dot);
            dot = __fmaf_rn(sp[p].z, c.z, dot);
            float d = __fsub_rn(__fadd_rn(sp[p].w, c.w), __fmul_rn(2.0f, dot));
            bool pred = (d <= tau[p]);
            u64 mk = __ballot(pred);
            if (mk != 0ull) {
                if (pred) {
                    int pos = base[p] + (int)__popcll(mk & ((1ull << lane) - 1ull));
                    if (pos < CAP2) { bufD[wv][p][pos] = d; bufJ[wv][p][pos] = j; }
                }
                base[p] += (int)__popcll(mk);
            }
        }
    }

    // ---- exact top-16 per point: lex-rank (d,j); slot = rank ----
#pragma unroll
    for (int p = 0; p < 4; ++p) {
        int ns = (base[p] > CAP2) ? CAP2 : base[p];   // >= 16 guaranteed
        for (int slot = 0; slot < 2; ++slot) {
            int sidx = slot * 64 + lane;
            if (sidx < ns) {
                float ds = bufD[wv][p][sidx];
                int   js = bufJ[wv][p][sidx];
                int rank = 0;
                for (int mm = 0; mm < ns; ++mm) {
                    float dm = bufD[wv][p][mm];
                    int   jm = bufJ[wv][p][mm];
                    rank += (dm < ds) || (dm == ds && jm < js);
                }
                if (rank < KNN) nbr_out_rows[(size_t)(pt0 + p) * 64 + rank] = js;
            }
        }
    }
}

// ============== KNN fallback (used only if ws too small) ==============
__global__ __launch_bounds__(256) void knn_kernel(const float* __restrict__ verts,
                                                  int* nbr_out_rows) {
    __shared__ float4 tilebuf[TILE];
    __shared__ float  bufD[4][CAP];
    __shared__ int    bufJ[4][CAP];

    const int tid = threadIdx.x, lane = tid & 63, wv = tid >> 6;
    const int pt = blockIdx.x * 4 + wv;
    const int b = pt >> 13, i = pt & (NPTS - 1);
    const float* vb = verts + (size_t)b * NPTS * 3;

    const float xi = vb[3 * i], yi = vb[3 * i + 1], zi = vb[3 * i + 2];
    const float sqi = __fadd_rn(__fadd_rn(__fmul_rn(xi, xi), __fmul_rn(yi, yi)),
                                __fmul_rn(zi, zi));

    float m_d = INFINITY;
    for (int t = 0; t < NPTS / TILE; ++t) {
        __syncthreads();
        for (int s = 0; s < TILE / 256; ++s) {
            int p = t * TILE + s * 256 + tid;
            float px = vb[3 * p], py = vb[3 * p + 1], pz = vb[3 * p + 2];
            float sq = __fadd_rn(__fadd_rn(__fmul_rn(px, px), __fmul_rn(py, py)),
                                 __fmul_rn(pz, pz));
            tilebuf[s * 256 + tid] = make_float4(px, py, pz, sq);
        }
        __syncthreads();
        for (int it = 0; it < TILE / 64; ++it) {
            float4 c = tilebuf[it * 64 + lane];
            float dot = __fmul_rn(xi, c.x);
            dot = __fmaf_rn(yi, c.y, dot);
            dot = __fmaf_rn(zi, c.z, dot);
            float d = __fsub_rn(__fadd_rn(sqi, c.w), __fmul_rn(2.0f, dot));
            m_d = fminf(m_d, d);
        }
    }
    __shared__ float minv[4][64];
    minv[wv][lane] = m_d;
    __syncthreads();
    int rnk = 0;
    for (int mm = 0; mm < 64; ++mm) {
        float vm = minv[wv][mm];
        rnk += (vm < m_d) || (vm == m_d && mm < lane);
    }
    u64 bal = __ballot(rnk == 15);
    float tau = __shfl(m_d, __ffsll(bal) - 1, 64);

    int base = 0;
    for (int t = 0; t < NPTS / TILE; ++t) {
        __syncthreads();
        for (int s = 0; s < TILE / 256; ++s) {
            int p = t * TILE + s * 256 + tid;
            float px = vb[3 * p], py = vb[3 * p + 1], pz = vb[3 * p + 2];
            float sq = __fadd_rn(__fadd_rn(__fmul_rn(px, px), __fmul_rn(py, py)),
                                 __fmul_rn(pz, pz));
            tilebuf[s * 256 + tid] = make_float4(px, py, pz, sq);
        }
        __syncthreads();
        for (int it = 0; it < TILE / 64; ++it) {
            int jl = it * 64 + lane;
            float4 c = tilebuf[jl];
            float dot = __fmul_rn(xi, c.x);
            dot = __fmaf_rn(yi, c.y, dot);
            dot = __fmaf_rn(zi, c.z, dot);
            float d = __fsub_rn(__fadd_rn(sqi, c.w), __fmul_rn(2.0f, dot));
            bool pred = (d <= tau);
            u64 mask = __ballot(pred);
            if (pred) {
                int pos = base + (int)__popcll(mask & ((1ull << lane) - 1ull));
                if (pos < CAP) { bufD[wv][pos] = d; bufJ[wv][pos] = t * TILE + jl; }
            }
            base += (int)__popcll(mask);
        }
    }
    int ns = (base > CAP) ? CAP : base;
    __syncthreads();
#pragma unroll
    for (int slot = 0; slot < 2; ++slot) {
        int sidx = slot * 64 + lane;
        if (sidx < ns) {
            float ds = bufD[wv][sidx];
            int   js = bufJ[wv][sidx];
            int rank = 0;
            for (int mm = 0; mm < ns; ++mm) {
                float dm = bufD[wv][mm];
                int   jm = bufJ[wv][mm];
                rank += (dm < ds) || (dm == ds && jm < js);
            }
            if (rank < KNN) nbr_out_rows[(size_t)pt * 64 + rank] = js;
        }
    }
}

// ============ MFMA edge MLP + mean + fused point MLP ============
__global__ __launch_bounds__(256, 2) void edge_kernel(
    const float* __restrict__ verts, const float* __restrict__ feats,
    const float* __restrict__ W1, const float* __restrict__ b1,
    const float* __restrict__ g1, const float* __restrict__ be1,
    const float* __restrict__ W2, const float* __restrict__ b2,
    const float* __restrict__ Wo1, const float* __restrict__ bo1,
    const float* __restrict__ go_, const float* __restrict__ beo,
    const float* __restrict__ Wo2, const float* __restrict__ bo2,
    float* out)   // rows hold knn idx on entry; final output on exit
{
    __shared__ u16 EP[G][4][64][8];     // 32 KB
    __shared__ u16 W1F[3][8][64][8];    // 24 KB (phase2: Wo1 frags in [0..1])
    __shared__ float b1s[HID], g1s[HID], be1s[HID];
    __shared__ float b2s[COUT];
    __shared__ float meansh[32][68];    // padded: stride 68 -> only 2-way conflicts
    __shared__ int   nbrs[G][KNN];

    const int tid  = threadIdx.x;
    const int lane = tid & 63, wv = tid >> 6;
    const int quad = lane >> 4, n16 = lane & 15;

    // ---- stage W1 as B-fragments ----
    for (int s = tid; s < 3 * 8 * 64; s += 256) {
        int kt = s >> 9, nt = (s >> 6) & 7, ln = s & 63;
        int q = ln >> 4, nn = ln & 15;
        int col = nt * 16 + nn;
        union { bf16x8 v; unsigned u[4]; } pk;
#pragma unroll
        for (int jj = 0; jj < 4; ++jj) {
            int k0 = kt * 32 + q * 8 + jj * 2;
            float a  = (k0     < EIN) ? W1[(size_t)k0 * HID + col]       : 0.0f;
            float bq = (k0 + 1 < EIN) ? W1[(size_t)(k0 + 1) * HID + col] : 0.0f;
            pk.u[jj] = pk2(a, bq);
        }
        *(bf16x8*)&W1F[kt][nt][ln][0] = pk.v;
    }
    if (tid < HID) { b1s[tid] = b1[tid]; g1s[tid] = g1[tid]; be1s[tid] = be1[tid]; }
    if (tid < COUT) b2s[tid] = b2[tid];

    // ---- W2 as B-fragments in registers ----
    bf16x8 w2r[4][4];
#pragma unroll
    for (int kt2 = 0; kt2 < 4; ++kt2)
#pragma unroll
        for (int nt2 = 0; nt2 < 4; ++nt2) {
            union { bf16x8 v; unsigned u[4]; } pk;
#pragma unroll
            for (int jj = 0; jj < 4; ++jj) {
                int k0 = kt2 * 32 + quad * 8 + jj * 2;
                int o = nt2 * 16 + n16;
                pk.u[jj] = pk2(W2[(size_t)k0 * COUT + o],
                               W2[(size_t)(k0 + 1) * COUT + o]);
            }
            w2r[kt2][nt2] = pk.v;
        }

    for (int g = 0; g < GROUPS; ++g) {
        const int P0 = (blockIdx.x * GROUPS + g) * G;
        const int bb = P0 >> 13;
        const float* fb  = feats + (size_t)bb * NPTS * CIN;
        const float* vbk = verts + (size_t)bb * NPTS * 3;

        __syncthreads();
        if (tid < G * KNN)
            nbrs[tid >> 4][tid & 15] =
                ((const int*)out)[(size_t)(P0 + (tid >> 4)) * 64 + (tid & 15)];
        __syncthreads();

        {   // gather E into A-frag layout
            int m = tid & 127;
            int p = m >> 4, k = m & 15;
            int coff = tid >> 7;
            int jn = nbrs[p][k];
            int ip = (P0 & (NPTS - 1)) + p;
#pragma unroll
            for (int it = 0; it < 6; ++it) {
                int c8 = it * 2 + coff;
                union { bf16x8 v; unsigned u[4]; } pk;
                if (c8 < 4) {
                    const float* src = fb + (size_t)jn * CIN + c8 * 8;
                    float4 A = *(const float4*)src, B4 = *(const float4*)(src + 4);
                    pk.u[0] = pk2(A.x, A.y); pk.u[1] = pk2(A.z, A.w);
                    pk.u[2] = pk2(B4.x, B4.y); pk.u[3] = pk2(B4.z, B4.w);
                } else if (c8 < 8) {
                    const float* src = fb + (size_t)ip * CIN + (c8 - 4) * 8;
                    float4 A = *(const float4*)src, B4 = *(const float4*)(src + 4);
                    pk.u[0] = pk2(A.x, A.y); pk.u[1] = pk2(A.z, A.w);
                    pk.u[2] = pk2(B4.x, B4.y); pk.u[3] = pk2(B4.z, B4.w);
                } else if (c8 == 8) {
                    float dx = vbk[3 * jn]     - vbk[3 * ip];
                    float dy = vbk[3 * jn + 1] - vbk[3 * ip + 1];
                    float dz = vbk[3 * jn + 2] - vbk[3 * ip + 2];
                    pk.u[0] = pk2(dx, dy); pk.u[1] = pk2(dz, 0.0f);
                    pk.u[2] = 0u; pk.u[3] = 0u;
                } else {
                    pk.u[0] = pk.u[1] = pk.u[2] = pk.u[3] = 0u;
                }
                *(bf16x8*)&EP[p][c8 >> 2][k + 16 * (c8 & 3)][0] = pk.v;
            }
        }
        __syncthreads();

#pragma unroll
        for (int half = 0; half < 2; ++half) {
            const int mt = wv + half * 4;

            f32x4 acc[8];
#pragma unroll
            for (int nt = 0; nt < 8; ++nt) acc[nt] = (f32x4){0.f, 0.f, 0.f, 0.f};
#pragma unroll
            for (int kt = 0; kt < 3; ++kt) {
                bf16x8 a = *(bf16x8*)&EP[mt][kt][lane][0];
#pragma unroll
                for (int nt = 0; nt < 8; ++nt) {
                    bf16x8 bfr = *(bf16x8*)&W1F[kt][nt][lane][0];
                    acc[nt] = __builtin_amdgcn_mfma_f32_16x16x32_bf16(a, bfr, acc[nt], 0, 0, 0);
                }
            }

            float b1v[8], g1v[8], bev[8];
#pragma unroll
            for (int nt = 0; nt < 8; ++nt) {
                b1v[nt] = b1s[nt * 16 + n16];
                g1v[nt] = g1s[nt * 16 + n16];
                bev[nt] = be1s[nt * 16 + n16];
            }
            float s1[4] = {0,0,0,0}, s2[4] = {0,0,0,0};
#pragma unroll
            for (int nt = 0; nt < 8; ++nt)
#pragma unroll
                for (int r = 0; r < 4; ++r) {
                    float x = acc[nt][r] + b1v[nt];
                    s1[r] += x; s2[r] += x * x;
                }
#pragma unroll
            for (int r = 0; r < 4; ++r) {
#pragma unroll
                for (int off = 1; off < 16; off <<= 1) {
                    s1[r] += __shfl_xor(s1[r], off, 64);
                    s2[r] += __shfl_xor(s2[r], off, 64);
                }
            }
            float mu[4], rs[4];
#pragma unroll
            for (int r = 0; r < 4; ++r) {
                mu[r] = s1[r] * (1.0f / HID);
                float var = s2[r] * (1.0f / HID) - mu[r] * mu[r];
                rs[r] = rsqrtf(var + 1e-5f);
            }

#pragma unroll
            for (int nt = 0; nt < 8; ++nt) {
                int kt2 = nt >> 1;
                int q2  = (nt * 2 + (n16 >> 3)) & 3;
                int jj  = n16 & 7;
#pragma unroll
                for (int r = 0; r < 4; ++r) {
                    float x  = acc[nt][r] + b1v[nt];
                    float xn = (x - mu[r]) * rs[r] * g1v[nt] + bev[nt];
                    EP[mt][kt2][quad * 4 + r + 16 * q2][jj] = (u16)f2b(gelu_t(xn));
                }
            }

            f32x4 acc2[4];
#pragma unroll
            for (int nt2 = 0; nt2 < 4; ++nt2) acc2[nt2] = (f32x4){0.f, 0.f, 0.f, 0.f};
#pragma unroll
            for (int kt2 = 0; kt2 < 4; ++kt2) {
                bf16x8 a2 = *(bf16x8*)&EP[mt][kt2][lane][0];
#pragma unroll
                for (int nt2 = 0; nt2 < 4; ++nt2)
                    acc2[nt2] = __builtin_amdgcn_mfma_f32_16x16x32_bf16(a2, w2r[kt2][nt2], acc2[nt2], 0, 0, 0);
            }

#pragma unroll
            for (int nt2 = 0; nt2 < 4; ++nt2) {
                float cs = acc2[nt2][0] + acc2[nt2][1] + acc2[nt2][2] + acc2[nt2][3];
                cs += __shfl_xor(cs, 16, 64);
                cs += __shfl_xor(cs, 32, 64);
                if (quad == 0) {
                    int o = nt2 * 16 + n16;
                    meansh[g * 8 + mt][o] = cs * (1.0f / KNN) + b2s[o];
                }
            }
        }
    }

    // ======== phase 2: point MLP (MFMA) for the block's 32 points ========
    __syncthreads();   // all groups done; safe to overlay W1F/EP/biases

    for (int s = tid; s < 2 * 8 * 64; s += 256) {   // Wo1 B-frags (K=64: kt 0..1)
        int kt = s >> 9, nt = (s >> 6) & 7, ln = s & 63;
        int q = ln >> 4, nn = ln & 15;
        int col = nt * 16 + nn;
        union { bf16x8 v; unsigned u[4]; } pk;
#pragma unroll
        for (int jj = 0; jj < 4; ++jj) {
            int k0 = kt * 32 + q * 8 + jj * 2;
            pk.u[jj] = pk2(Wo1[(size_t)k0 * HID + col],
                           Wo1[(size_t)(k0 + 1) * HID + col]);
        }
        *(bf16x8*)&W1F[kt][nt][ln][0] = pk.v;
    }
    if (tid < HID) { b1s[tid] = bo1[tid]; g1s[tid] = go_[tid]; be1s[tid] = beo[tid]; }
    if (tid < COUT) b2s[tid] = bo2[tid];
#pragma unroll
    for (int kt2 = 0; kt2 < 4; ++kt2)                // Wo2 -> w2r (same shape as W2)
#pragma unroll
        for (int nt2 = 0; nt2 < 4; ++nt2) {
            union { bf16x8 v; unsigned u[4]; } pk;
#pragma unroll
            for (int jj = 0; jj < 4; ++jj) {
                int k0 = kt2 * 32 + quad * 8 + jj * 2;
                int o = nt2 * 16 + n16;
                pk.u[jj] = pk2(Wo2[(size_t)k0 * COUT + o],
                               Wo2[(size_t)(k0 + 1) * COUT + o]);
            }
            w2r[kt2][nt2] = pk.v;
        }
    __syncthreads();

    if (wv < 2) {
        const int tile = wv;                         // 16 points per tile

        bf16x8 af[2];
#pragma unroll
        for (int kt = 0; kt < 2; ++kt) {             // A-frags from meansh
            const float* mrow = &meansh[tile * 16 + n16][kt * 32 + quad * 8];
            float4 A = *(const float4*)mrow, B4 = *(const float4*)(mrow + 4);
            union { bf16x8 v; unsigned u[4]; } pk;
            pk.u[0] = pk2(A.x, A.y); pk.u[1] = pk2(A.z, A.w);
            pk.u[2] = pk2(B4.x, B4.y); pk.u[3] = pk2(B4.z, B4.w);
            af[kt] = pk.v;
        }

        f32x4 acc[8];
#pragma unroll
        for (int nt = 0; nt < 8; ++nt) acc[nt] = (f32x4){0.f, 0.f, 0.f, 0.f};
#pragma unroll
        for (int kt = 0; kt < 2; ++kt)
#pragma unroll
            for (int nt = 0; nt < 8; ++nt) {
                bf16x8 bfr = *(bf16x8*)&W1F[kt][nt][lane][0];
                acc[nt] = __builtin_amdgcn_mfma_f32_16x16x32_bf16(af[kt], bfr, acc[nt], 0, 0, 0);
            }

        float b1v[8], g1v[8], bev[8];
#pragma unroll
        for (int nt = 0; nt < 8; ++nt) {
            b1v[nt] = b1s[nt * 16 + n16];
            g1v[nt] = g1s[nt * 16 + n16];
            bev[nt] = be1s[nt * 16 + n16];
        }
        float s1[4] = {0,0,0,0}, s2[4] = {0,0,0,0};
#pragma unroll
        for (int nt = 0; nt < 8; ++nt)
#pragma unroll
            for (int r = 0; r < 4; ++r) {
                float x = acc[nt][r] + b1v[nt];
                s1[r] += x; s2[r] += x * x;
            }
#pragma unroll
        for (int r = 0; r < 4; ++r) {
#pragma unroll
            for (int off = 1; off < 16; off <<= 1) {
                s1[r] += __shfl_xor(s1[r], off, 64);
                s2[r] += __shfl_xor(s2[r], off, 64);
            }
        }
#pragma unroll
        for (int nt = 0; nt < 8; ++nt) {
            int kt2 = nt >> 1;
            int q2  = (nt * 2 + (n16 >> 3)) & 3;
            int jj  = n16 & 7;
#pragma unroll
            for (int r = 0; r < 4; ++r) {
                float mu = s1[r] * (1.0f / HID);
                float var = s2[r] * (1.0f / HID) - mu * mu;
                float rs = rsqrtf(var + 1e-5f);
                float x  = acc[nt][r] + b1v[nt];
                float xn = (x - mu) * rs * g1v[nt] + bev[nt];
                EP[tile][kt2][quad * 4 + r + 16 * q2][jj] = (u16)f2b(gelu_t(xn));
            }
        }

        f32x4 acc2[4];
#pragma unroll
        for (int nt2 = 0; nt2 < 4; ++nt2) acc2[nt2] = (f32x4){0.f, 0.f, 0.f, 0.f};
#pragma unroll
        for (int kt2 = 0; kt2 < 4; ++kt2) {
            bf16x8 a2 = *(bf16x8*)&EP[tile][kt2][lane][0];
#pragma unroll
            for (int nt2 = 0; nt2 < 4; ++nt2)
                acc2[nt2] = __builtin_amdgcn_mfma_f32_16x16x32_bf16(a2, w2r[kt2][nt2], acc2[nt2], 0, 0, 0);
        }

#pragma unroll
        for (int nt2 = 0; nt2 < 4; ++nt2) {
            int o = nt2 * 16 + n16;
#pragma unroll
            for (int r = 0; r < 4; ++r) {
                int ptl = blockIdx.x * 32 + tile * 16 + quad * 4 + r;
                out[(size_t)ptl * 64 + o] = acc2[nt2][r] + b2s[o];
            }
        }
    }
}

extern "C" void kernel_launch(void* const* d_in, const int* in_sizes, int n_in,
                              void* d_out, int out_size, void* d_ws, size_t ws_size,
                              hipStream_t stream) {
    const float* verts = (const float*)d_in[0];
    const float* feats = (const float*)d_in[1];
    const float* W1  = (const float*)d_in[2];
    const float* b1  = (const float*)d_in[3];
    const float* g1  = (const float*)d_in[4];
    const float* be1 = (const float*)d_in[5];
    const float* W2  = (const float*)d_in[6];
    const float* b2  = (const float*)d_in[7];
    const float* Wo1 = (const float*)d_in[8];
    const float* bo1 = (const float*)d_in[9];
    const float* go_ = (const float*)d_in[10];
    const float* beo = (const float*)d_in[11];
    const float* Wo2 = (const float*)d_in[12];
    const float* bo2 = (const float*)d_in[13];
    float* out = (float*)d_out;

    (void)in_sizes; (void)n_in; (void)out_size;

    const size_t pv_bytes = (size_t)BATCH * NPTS * sizeof(float4);  // 256 KB
    if (ws_size >= pv_bytes) {
        float4* pv = (float4*)d_ws;
        prep_kernel<<<(BATCH * NPTS + 255) / 256, 256, 0, stream>>>(verts, pv);
        knn3_kernel<<<(BATCH * NPTS) / 16, 256, 0, stream>>>(pv, (int*)out);
    } else {
        knn_kernel<<<(BATCH * NPTS) / 4, 256, 0, stream>>>(verts, (int*)out);
    }
    edge_kernel<<<NBLK, 256, 0, stream>>>(
        verts, feats, W1, b1, g1, be1, W2, b2,
        Wo1, bo1, go_, beo, Wo2, bo2, out);
}